// Round 5
// baseline (705.890 us; speedup 1.0000x reference)
//
#include <hip/hip_runtime.h>

#define D 128
#define EPSV 1e-5f

typedef _Float16 f16;
typedef __attribute__((ext_vector_type(8))) _Float16 f16x8;
typedef __attribute__((ext_vector_type(4))) _Float16 f16x4;
typedef __attribute__((ext_vector_type(4))) float f32x4;

// ---------- fold BN of prev layer into W ----------
__global__ void fold_kernel(const float* __restrict__ W, const float* __restrict__ scsh,
                            int use_id, f16* __restrict__ Wfo, float* __restrict__ shW) {
    const int o = blockIdx.x;
    const int k = threadIdx.x;
    float w = W[o * D + k];
    float sc = use_id ? 1.0f : scsh[k];
    float sh = use_id ? 0.0f : scsh[D + k];
    Wfo[o * D + k] = (f16)(w * sc);
    float v = sh * w;
    #pragma unroll
    for (int off = 1; off < 64; off <<= 1) v += __shfl_xor(v, off, 64);
    __shared__ float red[2];
    if ((k & 63) == 0) red[k >> 6] = v;
    __syncthreads();
    if (k == 0) shW[o] = red[0] + red[1];
}

// ================= bucketized CSR build =================
__global__ __launch_bounds__(256) void bcount_kernel(const int* __restrict__ col,
                                                     int* __restrict__ gb, int E, int seg) {
    __shared__ int s[4096];
    for (int j = threadIdx.x; j < seg; j += 256) s[j] = 0;
    __syncthreads();
    int i = blockIdx.x * 256 + threadIdx.x;
    const int stride = gridDim.x * 256;
    for (; i < E; i += stride) {
        int b = col[i] >> 8;
        int p = (i >> 8) & 7;
        atomicAdd(&s[b * 8 + p], 1);
    }
    __syncthreads();
    for (int j = threadIdx.x; j < seg; j += 256)
        if (s[j]) atomicAdd(&gb[j], s[j]);
}

__global__ __launch_bounds__(1024) void bscan_kernel(const int* __restrict__ gb,
                                                     int* __restrict__ soff,
                                                     int* __restrict__ cur) {
    __shared__ int s[1024];
    const int tid = threadIdx.x;
    const int base = tid * 4;
    int g0 = gb[base], g1 = gb[base + 1], g2 = gb[base + 2], g3 = gb[base + 3];
    int my = g0 + g1 + g2 + g3;
    s[tid] = my;
    __syncthreads();
    for (int off = 1; off < 1024; off <<= 1) {
        int t = (tid >= off) ? s[tid - off] : 0;
        __syncthreads();
        s[tid] += t;
        __syncthreads();
    }
    int ex = s[tid] - my;
    soff[base] = ex;           cur[(base + 0) * 16] = ex;  ex += g0;
    soff[base + 1] = ex;       cur[(base + 1) * 16] = ex;  ex += g1;
    soff[base + 2] = ex;       cur[(base + 2) * 16] = ex;  ex += g2;
    soff[base + 3] = ex;       cur[(base + 3) * 16] = ex;
    if (tid == 1023) soff[4096] = s[1023];
}

__global__ __launch_bounds__(256) void bfill_kernel(const int* __restrict__ row,
                                                    const int* __restrict__ col,
                                                    int* __restrict__ cur,
                                                    int2* __restrict__ bpairs, int E) {
    int i = blockIdx.x * 256 + threadIdx.x;
    const int stride = gridDim.x * 256;   // gridDim %8==0 keeps p == (i>>8)&7
    for (; i < E; i += stride) {
        int c = col[i];
        int b = c >> 8;
        int p = (i >> 8) & 7;
        int pos = atomicAdd(&cur[(b * 8 + p) * 16], 1);
        bpairs[pos] = make_int2(row[i], c);
    }
}

__global__ __launch_bounds__(256) void bdeg_kernel(const int2* __restrict__ bpairs,
                                                   const int* __restrict__ soff,
                                                   int* __restrict__ deg,
                                                   float* __restrict__ dis, int N) {
    __shared__ int dc[256];
    const int b = blockIdx.x;
    const int tid = threadIdx.x;
    dc[tid] = 0;
    __syncthreads();
    const int s0 = soff[b * 8], s1 = soff[(b + 1) * 8];
    for (int k = s0 + tid; k < s1; k += 256)
        atomicAdd(&dc[bpairs[k].y & 255], 1);
    __syncthreads();
    int c = (b << 8) + tid;
    if (c < N) {
        int dv = dc[tid];
        deg[c] = dv;
        dis[c] = rsqrtf((float)dv + 1.0f);   // +1 = self loop
    }
}

__global__ void scan1_kernel(const int* __restrict__ cnt, int* __restrict__ offs,
                             int* __restrict__ bsum, int N) {
    __shared__ int s[256];
    int tid = threadIdx.x;
    int i = blockIdx.x * 256 + tid;
    int v = (i < N) ? cnt[i] : 0;
    s[tid] = v;
    __syncthreads();
    for (int off = 1; off < 256; off <<= 1) {
        int t = (tid >= off) ? s[tid - off] : 0;
        __syncthreads();
        s[tid] += t;
        __syncthreads();
    }
    if (i < N) offs[i] = s[tid] - v;
    if (tid == 255) bsum[blockIdx.x] = s[255];
}

__global__ void scan2_kernel(int* __restrict__ bsum, int NB) {
    __shared__ int s[512];
    int tid = threadIdx.x;
    int v = (tid < NB) ? bsum[tid] : 0;
    s[tid] = v;
    __syncthreads();
    for (int off = 1; off < 512; off <<= 1) {
        int t = (tid >= off) ? s[tid - off] : 0;
        __syncthreads();
        s[tid] += t;
        __syncthreads();
    }
    if (tid < NB) bsum[tid] = s[tid] - v;
}

__global__ void scan3_kernel(int* __restrict__ offs, const int* __restrict__ bsum,
                             int N, int E) {
    int i = blockIdx.x * 256 + threadIdx.x;
    if (i < N) offs[i] += bsum[blockIdx.x];
    if (i == 0) offs[N] = E;
}

__global__ __launch_bounds__(256) void cfill_kernel(const int2* __restrict__ bpairs,
                                                    const int* __restrict__ soff,
                                                    const int* __restrict__ offs,
                                                    int* __restrict__ srcs, int N) {
    __shared__ int lc[256];
    const int b = blockIdx.x;
    const int tid = threadIdx.x;
    int c = (b << 8) + tid;
    lc[tid] = (c < N) ? offs[c] : 0;
    __syncthreads();
    const int s0 = soff[b * 8], s1 = soff[(b + 1) * 8];
    for (int k = s0 + tid; k < s1; k += 256) {
        int2 pr = bpairs[k];
        int pos = atomicAdd(&lc[pr.y & 255], 1);
        srcs[pos] = pr.x;
    }
}

// ================= degree-descending counting sort =================
__global__ __launch_bounds__(256) void dhist_kernel(const int* __restrict__ deg,
                                                    int* __restrict__ hist, int N) {
    __shared__ int s[256];
    s[threadIdx.x] = 0;
    __syncthreads();
    int i = blockIdx.x * 256 + threadIdx.x;
    const int stride = gridDim.x * 256;
    for (; i < N; i += stride)
        atomicAdd(&s[255 - min(deg[i], 255)], 1);
    __syncthreads();
    if (s[threadIdx.x]) atomicAdd(&hist[threadIdx.x], s[threadIdx.x]);
}

__global__ void dscan_kernel(const int* __restrict__ hist, int* __restrict__ bcur) {
    __shared__ int s[256];
    int tid = threadIdx.x;
    int v = hist[tid];
    s[tid] = v;
    __syncthreads();
    for (int off = 1; off < 256; off <<= 1) {
        int t = (tid >= off) ? s[tid - off] : 0;
        __syncthreads();
        s[tid] += t;
        __syncthreads();
    }
    bcur[tid * 16] = s[tid] - v;
}

__global__ __launch_bounds__(256) void dorder_kernel(const int* __restrict__ deg,
                                                     int* __restrict__ bcur,
                                                     int* __restrict__ order, int N) {
    int i = blockIdx.x * 256 + threadIdx.x;
    const int stride = gridDim.x * 256;
    for (; i < N; i += stride) {
        int b = 255 - min(deg[i], 255);
        int pos = atomicAdd(&bcur[b * 16], 1);
        order[pos] = i;
    }
}

// ================= per-layer kernels =================

// ---- MFMA GEMM; xf32 != null => convert-on-load (layer 0) ----
__global__ __launch_bounds__(256) void gemm_kernel(
    const f16* __restrict__ xh, const float* __restrict__ xf32,
    const f16* __restrict__ Wfo, const float* __restrict__ shW,
    const float* __restrict__ dis, f16* __restrict__ h, int N, int nrg)
{
    const int lane = threadIdx.x & 63;
    const int l15 = lane & 15;
    const int lh = lane >> 4;

    f16x8 af[8][4];
    #pragma unroll
    for (int t = 0; t < 8; t++)
        #pragma unroll
        for (int kb = 0; kb < 4; kb++)
            af[t][kb] = *reinterpret_cast<const f16x8*>(
                &Wfo[(t * 16 + l15) * D + kb * 32 + lh * 8]);

    const int wid = (blockIdx.x * blockDim.x + threadIdx.x) >> 6;
    const int nwaves = (gridDim.x * blockDim.x) >> 6;

    for (int rg = wid; rg < nrg; rg += nwaves) {
        int row = rg * 16 + l15;
        int rrow = min(row, N - 1);
        f16x8 bf[4];
        if (xf32) {
            #pragma unroll
            for (int kb = 0; kb < 4; kb++) {
                const float* p = &xf32[(long long)rrow * D + kb * 32 + lh * 8];
                float4 u0 = *reinterpret_cast<const float4*>(p);
                float4 u1 = *reinterpret_cast<const float4*>(p + 4);
                f16x8 b;
                b[0] = (f16)u0.x; b[1] = (f16)u0.y; b[2] = (f16)u0.z; b[3] = (f16)u0.w;
                b[4] = (f16)u1.x; b[5] = (f16)u1.y; b[6] = (f16)u1.z; b[7] = (f16)u1.w;
                bf[kb] = b;
            }
        } else {
            #pragma unroll
            for (int kb = 0; kb < 4; kb++)
                bf[kb] = *reinterpret_cast<const f16x8*>(
                    &xh[(long long)rrow * D + kb * 32 + lh * 8]);
        }
        float d = dis[rrow];
        bool ok = (row < N);

        #pragma unroll
        for (int t = 0; t < 8; t++) {
            f32x4 acc = {0.0f, 0.0f, 0.0f, 0.0f};
            #pragma unroll
            for (int kb = 0; kb < 4; kb++)
                acc = __builtin_amdgcn_mfma_f32_16x16x32_f16(af[t][kb], bf[kb], acc, 0, 0, 0);
            int o0 = t * 16 + lh * 4;
            float4 sw = *reinterpret_cast<const float4*>(&shW[o0]);
            f16x4 ov;
            ov[0] = (f16)(d * (acc[0] + sw.x));
            ov[1] = (f16)(d * (acc[1] + sw.y));
            ov[2] = (f16)(d * (acc[2] + sw.z));
            ov[3] = (f16)(d * (acc[3] + sw.w));
            if (ok)
                *reinterpret_cast<f16x4*>(&h[(long long)row * D + o0]) = ov;
        }
    }
}

// ---- fused gather + finalize: 16 lanes/node, deg-sorted order, 4-deep loads ----
__global__ __launch_bounds__(256) void gather_kernel(
    const f16* __restrict__ h, const int* __restrict__ offs,
    const int* __restrict__ srcs, const int* __restrict__ order,
    const float* __restrict__ dis, const float* __restrict__ bias,
    f16* __restrict__ t, float* __restrict__ stats, int N)
{
    const int tid = threadIdx.x;
    const int l16 = tid & 15;
    const int grp = tid >> 4;            // 16 node-groups per block
    const int f8 = l16 * 8;
    float bv[8];
    {
        float4 ba = *reinterpret_cast<const float4*>(&bias[f8]);
        float4 bb = *reinterpret_cast<const float4*>(&bias[f8 + 4]);
        bv[0] = ba.x; bv[1] = ba.y; bv[2] = ba.z; bv[3] = ba.w;
        bv[4] = bb.x; bv[5] = bb.y; bv[6] = bb.z; bv[7] = bb.w;
    }
    float ssum[8] = {0, 0, 0, 0, 0, 0, 0, 0}, ssq[8] = {0, 0, 0, 0, 0, 0, 0, 0};

    for (int ci = blockIdx.x * 16 + grp; ci < N; ci += gridDim.x * 16) {
        const int c = order[ci];
        f16x8 hv = *reinterpret_cast<const f16x8*>(&h[(long long)c * D + f8]);  // self
        float a[8], a2[8];
        #pragma unroll
        for (int m = 0; m < 8; m++) { a[m] = (float)hv[m]; a2[m] = 0.0f; }
        const int k0 = offs[c], k1 = offs[c + 1];
        for (int kb = k0; kb < k1; kb += 16) {
            int kk = kb + l16;
            int rl = (kk < k1) ? srcs[kk] : 0;
            int cnt = min(16, k1 - kb);
            int j = 0;
            for (; j + 4 <= cnt; j += 4) {
                int r0 = __shfl(rl, j, 16);
                int r1 = __shfl(rl, j + 1, 16);
                int r2 = __shfl(rl, j + 2, 16);
                int r3 = __shfl(rl, j + 3, 16);
                f16x8 v0 = *reinterpret_cast<const f16x8*>(&h[(long long)r0 * D + f8]);
                f16x8 v1 = *reinterpret_cast<const f16x8*>(&h[(long long)r1 * D + f8]);
                f16x8 v2 = *reinterpret_cast<const f16x8*>(&h[(long long)r2 * D + f8]);
                f16x8 v3 = *reinterpret_cast<const f16x8*>(&h[(long long)r3 * D + f8]);
                #pragma unroll
                for (int m = 0; m < 8; m++) {
                    a[m] += (float)v0[m] + (float)v2[m];
                    a2[m] += (float)v1[m] + (float)v3[m];
                }
            }
            for (; j < cnt; j++) {
                int r0 = __shfl(rl, j, 16);
                f16x8 v0 = *reinterpret_cast<const f16x8*>(&h[(long long)r0 * D + f8]);
                #pragma unroll
                for (int m = 0; m < 8; m++) a[m] += (float)v0[m];
            }
        }
        float d = dis[c];
        float tv[8];
        float s = 0.0f;
        #pragma unroll
        for (int m = 0; m < 8; m++) {
            tv[m] = d * (a[m] + a2[m]) + bv[m];
            s += tv[m];
        }
        #pragma unroll
        for (int off = 1; off < 16; off <<= 1) s += __shfl_xor(s, off, 16);
        float mean = s * (1.0f / 128.0f);
        f16x8 ov;
        #pragma unroll
        for (int m = 0; m < 8; m++) {
            tv[m] -= mean;
            ov[m] = (f16)tv[m];
            ssum[m] += tv[m];
            ssq[m] += tv[m] * tv[m];
        }
        *reinterpret_cast<f16x8*>(&t[(long long)c * D + f8]) = ov;
    }

    __shared__ float red[256 * 16];
    #pragma unroll
    for (int j = 0; j < 8; j++) {
        red[tid * 16 + j] = ssum[j];
        red[tid * 16 + 8 + j] = ssq[j];
    }
    __syncthreads();
    const int o = tid;
    const int f = o & 127;
    const int sq = o >> 7;
    const int lf = f >> 3;
    const int j = f & 7;
    float v = 0;
    #pragma unroll
    for (int g = 0; g < 16; g++)
        v += red[(g * 16 + lf) * 16 + sq * 8 + j];
    unsafeAtomicAdd(&stats[o], v);
}

// ---- fold BN stats into scale/shift ----
__global__ void stats_kernel(const float* __restrict__ stats,
                             const float* __restrict__ gamma,
                             const float* __restrict__ beta,
                             float* __restrict__ scsh, float Ninv)
{
    int j = threadIdx.x;
    float mu = stats[j] * Ninv;
    float var = stats[D + j] * Ninv - mu * mu;
    float inv = rsqrtf(var + EPSV);
    float sc = gamma[j] * inv;
    scsh[j] = sc;
    scsh[D + j] = beta[j] - mu * sc;
}

// ---- final BN apply: out(f32) = t(fp16)*sc + sh ----
__global__ __launch_bounds__(256) void epi2_kernel(
    const f16* __restrict__ t, const float* __restrict__ scsh,
    float* __restrict__ out, long long total4)
{
    __shared__ float sc[D], sh[D];
    if (threadIdx.x < D) {
        sc[threadIdx.x] = scsh[threadIdx.x];
        sh[threadIdx.x] = scsh[D + threadIdx.x];
    }
    __syncthreads();
    long long i = (long long)blockIdx.x * blockDim.x + threadIdx.x;
    const long long stride = (long long)gridDim.x * blockDim.x;
    for (; i < total4; i += stride) {
        f16x4 v = reinterpret_cast<const f16x4*>(t)[i];
        int f0 = (int)((i * 4) & (D - 1));
        float4 o;
        o.x = (float)v[0] * sc[f0 + 0] + sh[f0 + 0];
        o.y = (float)v[1] * sc[f0 + 1] + sh[f0 + 1];
        o.z = (float)v[2] * sc[f0 + 2] + sh[f0 + 2];
        o.w = (float)v[3] * sc[f0 + 3] + sh[f0 + 3];
        reinterpret_cast<float4*>(out)[i] = o;
    }
}

extern "C" void kernel_launch(void* const* d_in, const int* in_sizes, int n_in,
                              void* d_out, int out_size, void* d_ws, size_t ws_size,
                              hipStream_t stream)
{
    const float* x_in  = (const float*)d_in[0];
    const int*   ei    = (const int*)d_in[1];
    const float* W     = (const float*)d_in[2];
    const float* bias  = (const float*)d_in[3];
    const float* gamma = (const float*)d_in[4];
    const float* beta  = (const float*)d_in[5];

    const int N = in_sizes[0] / D;
    const int E = in_sizes[1] / 2;
    const int L = in_sizes[2] / (D * D);
    const int* row = ei;           // source
    const int* col = ei + E;       // target
    const int NB = (N + 255) / 256;
    const int NBUCK = (N + 255) >> 8;
    const int seg = NBUCK * 8;
    const int nrg = (N + 15) / 16;

    // ws layout
    f16* tbuf = (f16*)d_ws;
    f16* hbuf = tbuf + (size_t)N * D;
    f16* Wfo  = hbuf + (size_t)N * D;
    float* dis   = (float*)(Wfo + D * D);
    float* stats = dis + N;
    float* scsh  = stats + 2 * D;
    float* shW   = scsh + 2 * D;
    int* deg   = (int*)(shW + D);
    int* offs  = deg + N;
    int* srcs  = offs + (N + 1);
    int* bsum  = srcs + E;
    int* gb    = bsum + 512;
    int* soff  = gb + 4096;
    int* cur   = soff + 4097;
    int* hist  = cur + 4096 * 16;
    int* bcur  = hist + 256;
    int* order = bcur + 256 * 16;
    size_t used = (size_t)(order + N - (int*)d_ws);
    int2* bpairs = (int2*)((int*)d_ws + ((used + 1) & ~(size_t)1));

    // ---- CSR build ----
    hipMemsetAsync(gb, 0, 4096 * sizeof(int), stream);
    hipMemsetAsync(hist, 0, 256 * sizeof(int), stream);
    bcount_kernel<<<128, 256, 0, stream>>>(col, gb, E, seg);
    bscan_kernel<<<1, 1024, 0, stream>>>(gb, soff, cur);
    bfill_kernel<<<1024, 256, 0, stream>>>(row, col, cur, bpairs, E);
    bdeg_kernel<<<NBUCK, 256, 0, stream>>>(bpairs, soff, deg, dis, N);
    scan1_kernel<<<NB, 256, 0, stream>>>(deg, offs, bsum, N);
    scan2_kernel<<<1, 512, 0, stream>>>(bsum, NB);
    scan3_kernel<<<NB, 256, 0, stream>>>(offs, bsum, N, E);
    cfill_kernel<<<NBUCK, 256, 0, stream>>>(bpairs, soff, offs, srcs, N);
    // ---- degree-descending order ----
    dhist_kernel<<<128, 256, 0, stream>>>(deg, hist, N);
    dscan_kernel<<<1, 256, 0, stream>>>(hist, bcur);
    dorder_kernel<<<128, 256, 0, stream>>>(deg, bcur, order, N);

    const float Ninv = 1.0f / (float)N;
    const long long total4 = (long long)N * D / 4;

    fold_kernel<<<D, D, 0, stream>>>(W, scsh, 1, Wfo, shW);   // layer 0: identity fold

    for (int l = 0; l < L; l++) {
        gemm_kernel<<<512, 256, 0, stream>>>(
            tbuf, (l == 0) ? x_in : nullptr, Wfo, shW, dis, hbuf, N, nrg);
        hipMemsetAsync(stats, 0, 2 * D * sizeof(float), stream);
        gather_kernel<<<2048, 256, 0, stream>>>(
            hbuf, offs, srcs, order, dis, bias + (size_t)l * D, tbuf, stats, N);
        stats_kernel<<<1, D, 0, stream>>>(
            stats, gamma + (size_t)l * D, beta + (size_t)l * D, scsh, Ninv);
        if (l < L - 1)
            fold_kernel<<<D, D, 0, stream>>>(W + (size_t)(l + 1) * D * D, scsh, 0, Wfo, shW);
        else
            epi2_kernel<<<4096, 256, 0, stream>>>(tbuf, scsh, (float*)d_out, total4);
    }
}

// Round 6
// 484.356 us; speedup vs baseline: 1.4574x; 1.4574x over previous
//
#include <hip/hip_runtime.h>

#define D 128
#define EPSV 1e-5f

typedef _Float16 f16;
typedef __attribute__((ext_vector_type(8))) _Float16 f16x8;
typedef __attribute__((ext_vector_type(4))) _Float16 f16x4;
typedef __attribute__((ext_vector_type(4))) float f32x4;

// ---------- fold BN of prev layer into W ----------
__global__ void fold_kernel(const float* __restrict__ W, const float* __restrict__ scsh,
                            int use_id, f16* __restrict__ Wfo, float* __restrict__ shW) {
    const int o = blockIdx.x;
    const int k = threadIdx.x;
    float w = W[o * D + k];
    float sc = use_id ? 1.0f : scsh[k];
    float sh = use_id ? 0.0f : scsh[D + k];
    Wfo[o * D + k] = (f16)(w * sc);
    float v = sh * w;
    #pragma unroll
    for (int off = 1; off < 64; off <<= 1) v += __shfl_xor(v, off, 64);
    __shared__ float red[2];
    if ((k & 63) == 0) red[k >> 6] = v;
    __syncthreads();
    if (k == 0) shW[o] = red[0] + red[1];
}

// ================= bucketized CSR build =================
__global__ __launch_bounds__(256) void bcount_kernel(const int* __restrict__ col,
                                                     int* __restrict__ gb, int E, int seg) {
    __shared__ int s[4096];
    for (int j = threadIdx.x; j < seg; j += 256) s[j] = 0;
    __syncthreads();
    int i = blockIdx.x * 256 + threadIdx.x;
    const int stride = gridDim.x * 256;
    for (; i < E; i += stride) {
        int b = col[i] >> 8;
        int p = (i >> 8) & 7;
        atomicAdd(&s[b * 8 + p], 1);
    }
    __syncthreads();
    for (int j = threadIdx.x; j < seg; j += 256)
        if (s[j]) atomicAdd(&gb[j], s[j]);
}

__global__ __launch_bounds__(1024) void bscan_kernel(const int* __restrict__ gb,
                                                     int* __restrict__ soff,
                                                     int* __restrict__ cur) {
    __shared__ int s[1024];
    const int tid = threadIdx.x;
    const int base = tid * 4;
    int g0 = gb[base], g1 = gb[base + 1], g2 = gb[base + 2], g3 = gb[base + 3];
    int my = g0 + g1 + g2 + g3;
    s[tid] = my;
    __syncthreads();
    for (int off = 1; off < 1024; off <<= 1) {
        int t = (tid >= off) ? s[tid - off] : 0;
        __syncthreads();
        s[tid] += t;
        __syncthreads();
    }
    int ex = s[tid] - my;
    soff[base] = ex;           cur[(base + 0) * 16] = ex;  ex += g0;
    soff[base + 1] = ex;       cur[(base + 1) * 16] = ex;  ex += g1;
    soff[base + 2] = ex;       cur[(base + 2) * 16] = ex;  ex += g2;
    soff[base + 3] = ex;       cur[(base + 3) * 16] = ex;
    if (tid == 1023) soff[4096] = s[1023];
}

__global__ __launch_bounds__(256) void bfill_kernel(const int* __restrict__ row,
                                                    const int* __restrict__ col,
                                                    int* __restrict__ cur,
                                                    int2* __restrict__ bpairs, int E) {
    int i = blockIdx.x * 256 + threadIdx.x;
    const int stride = gridDim.x * 256;   // gridDim %8==0 keeps p == (i>>8)&7
    for (; i < E; i += stride) {
        int c = col[i];
        int b = c >> 8;
        int p = (i >> 8) & 7;
        int pos = atomicAdd(&cur[(b * 8 + p) * 16], 1);
        bpairs[pos] = make_int2(row[i], c);
    }
}

__global__ __launch_bounds__(256) void bdeg_kernel(const int2* __restrict__ bpairs,
                                                   const int* __restrict__ soff,
                                                   int* __restrict__ deg,
                                                   float* __restrict__ dis, int N) {
    __shared__ int dc[256];
    const int b = blockIdx.x;
    const int tid = threadIdx.x;
    dc[tid] = 0;
    __syncthreads();
    const int s0 = soff[b * 8], s1 = soff[(b + 1) * 8];
    for (int k = s0 + tid; k < s1; k += 256)
        atomicAdd(&dc[bpairs[k].y & 255], 1);
    __syncthreads();
    int c = (b << 8) + tid;
    if (c < N) {
        int dv = dc[tid];
        deg[c] = dv;
        dis[c] = rsqrtf((float)dv + 1.0f);   // +1 = self loop
    }
}

__global__ void scan1_kernel(const int* __restrict__ cnt, int* __restrict__ offs,
                             int* __restrict__ bsum, int N) {
    __shared__ int s[256];
    int tid = threadIdx.x;
    int i = blockIdx.x * 256 + tid;
    int v = (i < N) ? cnt[i] : 0;
    s[tid] = v;
    __syncthreads();
    for (int off = 1; off < 256; off <<= 1) {
        int t = (tid >= off) ? s[tid - off] : 0;
        __syncthreads();
        s[tid] += t;
        __syncthreads();
    }
    if (i < N) offs[i] = s[tid] - v;
    if (tid == 255) bsum[blockIdx.x] = s[255];
}

__global__ void scan2_kernel(int* __restrict__ bsum, int NB) {
    __shared__ int s[512];
    int tid = threadIdx.x;
    int v = (tid < NB) ? bsum[tid] : 0;
    s[tid] = v;
    __syncthreads();
    for (int off = 1; off < 512; off <<= 1) {
        int t = (tid >= off) ? s[tid - off] : 0;
        __syncthreads();
        s[tid] += t;
        __syncthreads();
    }
    if (tid < NB) bsum[tid] = s[tid] - v;
}

__global__ void scan3_kernel(int* __restrict__ offs, const int* __restrict__ bsum,
                             int N, int E) {
    int i = blockIdx.x * 256 + threadIdx.x;
    if (i < N) offs[i] += bsum[blockIdx.x];
    if (i == 0) offs[N] = E;
}

__global__ __launch_bounds__(256) void cfill_kernel(const int2* __restrict__ bpairs,
                                                    const int* __restrict__ soff,
                                                    const int* __restrict__ offs,
                                                    int* __restrict__ srcs, int N) {
    __shared__ int lc[256];
    const int b = blockIdx.x;
    const int tid = threadIdx.x;
    int c = (b << 8) + tid;
    lc[tid] = (c < N) ? offs[c] : 0;
    __syncthreads();
    const int s0 = soff[b * 8], s1 = soff[(b + 1) * 8];
    for (int k = s0 + tid; k < s1; k += 256) {
        int2 pr = bpairs[k];
        int pos = atomicAdd(&lc[pr.y & 255], 1);
        srcs[pos] = pr.x;
    }
}

// ---- tile-local degree sort: each 256-node tile sorted desc by degree (LDS counting sort) ----
__global__ __launch_bounds__(256) void tsort_kernel(const int* __restrict__ deg,
                                                    int* __restrict__ order, int N) {
    __shared__ int hist[256];
    __shared__ int cur[256];
    __shared__ int cur2[256];
    const int tid = threadIdx.x;
    const int i = blockIdx.x * 256 + tid;
    hist[tid] = 0;
    __syncthreads();
    int b = 0;
    if (i < N) {
        b = 255 - min(deg[i], 255);
        atomicAdd(&hist[b], 1);
    }
    __syncthreads();
    int v = hist[tid];
    cur[tid] = v;
    __syncthreads();
    for (int off = 1; off < 256; off <<= 1) {
        int t = (tid >= off) ? cur[tid - off] : 0;
        __syncthreads();
        cur[tid] += t;
        __syncthreads();
    }
    cur2[tid] = cur[tid] - v;       // exclusive
    __syncthreads();
    if (i < N) {
        int pos = atomicAdd(&cur2[b], 1);
        order[blockIdx.x * 256 + pos] = i;   // valid nodes fill tile positions densely
    }
}

// ================= per-layer kernels =================

// ---- MFMA GEMM; xf32 != null => convert-on-load (layer 0) ----
__global__ __launch_bounds__(256) void gemm_kernel(
    const f16* __restrict__ xh, const float* __restrict__ xf32,
    const f16* __restrict__ Wfo, const float* __restrict__ shW,
    const float* __restrict__ dis, f16* __restrict__ h, int N, int nrg)
{
    const int lane = threadIdx.x & 63;
    const int l15 = lane & 15;
    const int lh = lane >> 4;

    f16x8 af[8][4];
    #pragma unroll
    for (int t = 0; t < 8; t++)
        #pragma unroll
        for (int kb = 0; kb < 4; kb++)
            af[t][kb] = *reinterpret_cast<const f16x8*>(
                &Wfo[(t * 16 + l15) * D + kb * 32 + lh * 8]);

    const int wid = (blockIdx.x * blockDim.x + threadIdx.x) >> 6;
    const int nwaves = (gridDim.x * blockDim.x) >> 6;

    for (int rg = wid; rg < nrg; rg += nwaves) {
        int row = rg * 16 + l15;
        int rrow = min(row, N - 1);
        f16x8 bf[4];
        if (xf32) {
            #pragma unroll
            for (int kb = 0; kb < 4; kb++) {
                const float* p = &xf32[(long long)rrow * D + kb * 32 + lh * 8];
                float4 u0 = *reinterpret_cast<const float4*>(p);
                float4 u1 = *reinterpret_cast<const float4*>(p + 4);
                f16x8 b;
                b[0] = (f16)u0.x; b[1] = (f16)u0.y; b[2] = (f16)u0.z; b[3] = (f16)u0.w;
                b[4] = (f16)u1.x; b[5] = (f16)u1.y; b[6] = (f16)u1.z; b[7] = (f16)u1.w;
                bf[kb] = b;
            }
        } else {
            #pragma unroll
            for (int kb = 0; kb < 4; kb++)
                bf[kb] = *reinterpret_cast<const f16x8*>(
                    &xh[(long long)rrow * D + kb * 32 + lh * 8]);
        }
        float d = dis[rrow];
        bool ok = (row < N);

        #pragma unroll
        for (int t = 0; t < 8; t++) {
            f32x4 acc = {0.0f, 0.0f, 0.0f, 0.0f};
            #pragma unroll
            for (int kb = 0; kb < 4; kb++)
                acc = __builtin_amdgcn_mfma_f32_16x16x32_f16(af[t][kb], bf[kb], acc, 0, 0, 0);
            int o0 = t * 16 + lh * 4;
            float4 sw = *reinterpret_cast<const float4*>(&shW[o0]);
            f16x4 ov;
            ov[0] = (f16)(d * (acc[0] + sw.x));
            ov[1] = (f16)(d * (acc[1] + sw.y));
            ov[2] = (f16)(d * (acc[2] + sw.z));
            ov[3] = (f16)(d * (acc[3] + sw.w));
            if (ok)
                *reinterpret_cast<f16x4*>(&h[(long long)row * D + o0]) = ov;
        }
    }
}

// ---- fused gather + finalize: 16 lanes/node, tile-sorted order, 4-deep loads ----
__global__ __launch_bounds__(256) void gather_kernel(
    const f16* __restrict__ h, const int* __restrict__ offs,
    const int* __restrict__ srcs, const int* __restrict__ order,
    const float* __restrict__ dis, const float* __restrict__ bias,
    f16* __restrict__ t, float* __restrict__ stats, int N)
{
    const int tid = threadIdx.x;
    const int l16 = tid & 15;
    const int grp = tid >> 4;            // 16 node-groups per block
    const int f8 = l16 * 8;
    float bv[8];
    {
        float4 ba = *reinterpret_cast<const float4*>(&bias[f8]);
        float4 bb = *reinterpret_cast<const float4*>(&bias[f8 + 4]);
        bv[0] = ba.x; bv[1] = ba.y; bv[2] = ba.z; bv[3] = ba.w;
        bv[4] = bb.x; bv[5] = bb.y; bv[6] = bb.z; bv[7] = bb.w;
    }
    float ssum[8] = {0, 0, 0, 0, 0, 0, 0, 0}, ssq[8] = {0, 0, 0, 0, 0, 0, 0, 0};

    for (int ci = blockIdx.x * 16 + grp; ci < N; ci += gridDim.x * 16) {
        const int c = order[ci];
        f16x8 hv = *reinterpret_cast<const f16x8*>(&h[(long long)c * D + f8]);  // self
        float a[8], a2[8];
        #pragma unroll
        for (int m = 0; m < 8; m++) { a[m] = (float)hv[m]; a2[m] = 0.0f; }
        const int k0 = offs[c], k1 = offs[c + 1];
        for (int kb = k0; kb < k1; kb += 16) {
            int kk = kb + l16;
            int rl = (kk < k1) ? srcs[kk] : 0;
            int cnt = min(16, k1 - kb);
            int j = 0;
            for (; j + 4 <= cnt; j += 4) {
                int r0 = __shfl(rl, j, 16);
                int r1 = __shfl(rl, j + 1, 16);
                int r2 = __shfl(rl, j + 2, 16);
                int r3 = __shfl(rl, j + 3, 16);
                f16x8 v0 = *reinterpret_cast<const f16x8*>(&h[(long long)r0 * D + f8]);
                f16x8 v1 = *reinterpret_cast<const f16x8*>(&h[(long long)r1 * D + f8]);
                f16x8 v2 = *reinterpret_cast<const f16x8*>(&h[(long long)r2 * D + f8]);
                f16x8 v3 = *reinterpret_cast<const f16x8*>(&h[(long long)r3 * D + f8]);
                #pragma unroll
                for (int m = 0; m < 8; m++) {
                    a[m] += (float)v0[m] + (float)v2[m];
                    a2[m] += (float)v1[m] + (float)v3[m];
                }
            }
            for (; j < cnt; j++) {
                int r0 = __shfl(rl, j, 16);
                f16x8 v0 = *reinterpret_cast<const f16x8*>(&h[(long long)r0 * D + f8]);
                #pragma unroll
                for (int m = 0; m < 8; m++) a[m] += (float)v0[m];
            }
        }
        float d = dis[c];
        float tv[8];
        float s = 0.0f;
        #pragma unroll
        for (int m = 0; m < 8; m++) {
            tv[m] = d * (a[m] + a2[m]) + bv[m];
            s += tv[m];
        }
        #pragma unroll
        for (int off = 1; off < 16; off <<= 1) s += __shfl_xor(s, off, 16);
        float mean = s * (1.0f / 128.0f);
        f16x8 ov;
        #pragma unroll
        for (int m = 0; m < 8; m++) {
            tv[m] -= mean;
            ov[m] = (f16)tv[m];
            ssum[m] += tv[m];
            ssq[m] += tv[m] * tv[m];
        }
        *reinterpret_cast<f16x8*>(&t[(long long)c * D + f8]) = ov;
    }

    __shared__ float red[256 * 16];
    #pragma unroll
    for (int j = 0; j < 8; j++) {
        red[tid * 16 + j] = ssum[j];
        red[tid * 16 + 8 + j] = ssq[j];
    }
    __syncthreads();
    const int o = tid;
    const int f = o & 127;
    const int sq = o >> 7;
    const int lf = f >> 3;
    const int j = f & 7;
    float v = 0;
    #pragma unroll
    for (int g = 0; g < 16; g++)
        v += red[(g * 16 + lf) * 16 + sq * 8 + j];
    unsafeAtomicAdd(&stats[o], v);
}

// ---- fold BN stats into scale/shift ----
__global__ void stats_kernel(const float* __restrict__ stats,
                             const float* __restrict__ gamma,
                             const float* __restrict__ beta,
                             float* __restrict__ scsh, float Ninv)
{
    int j = threadIdx.x;
    float mu = stats[j] * Ninv;
    float var = stats[D + j] * Ninv - mu * mu;
    float inv = rsqrtf(var + EPSV);
    float sc = gamma[j] * inv;
    scsh[j] = sc;
    scsh[D + j] = beta[j] - mu * sc;
}

// ---- final BN apply: out(f32) = t(fp16)*sc + sh ----
__global__ __launch_bounds__(256) void epi2_kernel(
    const f16* __restrict__ t, const float* __restrict__ scsh,
    float* __restrict__ out, long long total4)
{
    __shared__ float sc[D], sh[D];
    if (threadIdx.x < D) {
        sc[threadIdx.x] = scsh[threadIdx.x];
        sh[threadIdx.x] = scsh[D + threadIdx.x];
    }
    __syncthreads();
    long long i = (long long)blockIdx.x * blockDim.x + threadIdx.x;
    const long long stride = (long long)gridDim.x * blockDim.x;
    for (; i < total4; i += stride) {
        f16x4 v = reinterpret_cast<const f16x4*>(t)[i];
        int f0 = (int)((i * 4) & (D - 1));
        float4 o;
        o.x = (float)v[0] * sc[f0 + 0] + sh[f0 + 0];
        o.y = (float)v[1] * sc[f0 + 1] + sh[f0 + 1];
        o.z = (float)v[2] * sc[f0 + 2] + sh[f0 + 2];
        o.w = (float)v[3] * sc[f0 + 3] + sh[f0 + 3];
        reinterpret_cast<float4*>(out)[i] = o;
    }
}

extern "C" void kernel_launch(void* const* d_in, const int* in_sizes, int n_in,
                              void* d_out, int out_size, void* d_ws, size_t ws_size,
                              hipStream_t stream)
{
    const float* x_in  = (const float*)d_in[0];
    const int*   ei    = (const int*)d_in[1];
    const float* W     = (const float*)d_in[2];
    const float* bias  = (const float*)d_in[3];
    const float* gamma = (const float*)d_in[4];
    const float* beta  = (const float*)d_in[5];

    const int N = in_sizes[0] / D;
    const int E = in_sizes[1] / 2;
    const int L = in_sizes[2] / (D * D);
    const int* row = ei;           // source
    const int* col = ei + E;       // target
    const int NB = (N + 255) / 256;
    const int NBUCK = (N + 255) >> 8;
    const int seg = NBUCK * 8;
    const int nrg = (N + 15) / 16;

    // ws layout
    f16* tbuf = (f16*)d_ws;
    f16* hbuf = tbuf + (size_t)N * D;
    f16* Wfo  = hbuf + (size_t)N * D;
    float* dis   = (float*)(Wfo + D * D);
    float* stats = dis + N;
    float* scsh  = stats + 2 * D;
    float* shW   = scsh + 2 * D;
    int* deg   = (int*)(shW + D);
    int* offs  = deg + N;
    int* srcs  = offs + (N + 1);
    int* bsum  = srcs + E;
    int* gb    = bsum + 512;
    int* soff  = gb + 4096;
    int* cur   = soff + 4097;
    int* order = cur + 4096 * 16;
    size_t used = (size_t)(order + N - (int*)d_ws);
    int2* bpairs = (int2*)((int*)d_ws + ((used + 1) & ~(size_t)1));

    // ---- CSR build ----
    hipMemsetAsync(gb, 0, 4096 * sizeof(int), stream);
    bcount_kernel<<<128, 256, 0, stream>>>(col, gb, E, seg);
    bscan_kernel<<<1, 1024, 0, stream>>>(gb, soff, cur);
    bfill_kernel<<<1024, 256, 0, stream>>>(row, col, cur, bpairs, E);
    bdeg_kernel<<<NBUCK, 256, 0, stream>>>(bpairs, soff, deg, dis, N);
    scan1_kernel<<<NB, 256, 0, stream>>>(deg, offs, bsum, N);
    scan2_kernel<<<1, 512, 0, stream>>>(bsum, NB);
    scan3_kernel<<<NB, 256, 0, stream>>>(offs, bsum, N, E);
    cfill_kernel<<<NBUCK, 256, 0, stream>>>(bpairs, soff, offs, srcs, N);
    tsort_kernel<<<NB, 256, 0, stream>>>(deg, order, N);   // tile-local degree sort

    const float Ninv = 1.0f / (float)N;
    const long long total4 = (long long)N * D / 4;

    fold_kernel<<<D, D, 0, stream>>>(W, scsh, 1, Wfo, shW);   // layer 0: identity fold

    for (int l = 0; l < L; l++) {
        gemm_kernel<<<512, 256, 0, stream>>>(
            tbuf, (l == 0) ? x_in : nullptr, Wfo, shW, dis, hbuf, N, nrg);
        hipMemsetAsync(stats, 0, 2 * D * sizeof(float), stream);
        gather_kernel<<<2048, 256, 0, stream>>>(
            hbuf, offs, srcs, order, dis, bias + (size_t)l * D, tbuf, stats, N);
        stats_kernel<<<1, D, 0, stream>>>(
            stats, gamma + (size_t)l * D, beta + (size_t)l * D, scsh, Ninv);
        if (l < L - 1)
            fold_kernel<<<D, D, 0, stream>>>(W + (size_t)(l + 1) * D * D, scsh, 0, Wfo, shW);
        else
            epi2_kernel<<<4096, 256, 0, stream>>>(tbuf, scsh, (float*)d_out, total4);
    }
}